// Round 1
// baseline (989.284 us; speedup 1.0000x reference)
//
#include <hip/hip_runtime.h>
#include <hip/hip_bf16.h>
#include <math.h>

// Problem constants (fixed by reference)
#define NT  8192
#define EMB 512
#define DFF 2048
#define EPS 1e-5f
#define SCALE 0.04419417382415922f  // 1/sqrt(512)

typedef __hip_bfloat16 bf16;
typedef __attribute__((ext_vector_type(8))) short short8;
typedef __attribute__((ext_vector_type(4))) float floatx4;

#define MFMA16(a, b, c) __builtin_amdgcn_mfma_f32_16x16x32_bf16((a), (b), (c), 0, 0, 0)

__device__ __forceinline__ void async16(const void* g, void* l) {
  __builtin_amdgcn_global_load_lds(
      (const __attribute__((address_space(1))) void*)g,
      (__attribute__((address_space(3))) void*)l, 16, 0, 0);
}

// ---------------- LayerNorm: fp32 in -> bf16 out, one row per block ----------------
__global__ __launch_bounds__(512) void ln_kernel(const float* __restrict__ in,
                                                 const float* __restrict__ g,
                                                 const float* __restrict__ b,
                                                 bf16* __restrict__ out) {
  const int row = blockIdx.x;
  const int tid = threadIdx.x;
  float v = in[(size_t)row * EMB + tid];
  float s = v, ss = v * v;
#pragma unroll
  for (int m = 1; m < 64; m <<= 1) {
    s += __shfl_xor(s, m, 64);
    ss += __shfl_xor(ss, m, 64);
  }
  __shared__ float ps[8], pss[8], mu_s, ri_s;
  const int wave = tid >> 6;
  if ((tid & 63) == 0) { ps[wave] = s; pss[wave] = ss; }
  __syncthreads();
  if (tid == 0) {
    float S = 0.f, SS = 0.f;
#pragma unroll
    for (int w = 0; w < 8; ++w) { S += ps[w]; SS += pss[w]; }
    float mu = S * (1.0f / EMB);
    float var = SS * (1.0f / EMB) - mu * mu;
    mu_s = mu;
    ri_s = rsqrtf(var + EPS);
  }
  __syncthreads();
  float y = (v - mu_s) * ri_s * g[tid] + b[tid];
  out[(size_t)row * EMB + tid] = __float2bfloat16(y);
}

// ---------------- transpose + cast to bf16: out[c][r] = in[r][c] ----------------
template <typename Tin>
__global__ void transpose_cast(const Tin* __restrict__ in, bf16* __restrict__ out,
                               int R, int C) {
  __shared__ float tile[32][33];
  const int r0 = blockIdx.x * 32, c0 = blockIdx.y * 32;
  const int x = threadIdx.x, y = threadIdx.y;  // block (32, 8)
#pragma unroll
  for (int i = 0; i < 4; ++i)
    tile[y + 8 * i][x] = (float)in[(size_t)(r0 + y + 8 * i) * C + c0 + x];
  __syncthreads();
#pragma unroll
  for (int i = 0; i < 4; ++i)
    out[(size_t)(c0 + y + 8 * i) * R + r0 + x] = __float2bfloat16(tile[x][y + 8 * i]);
}

// ---------------- Flash attention ----------------
// Q=K=V=norm_x (bf16), bias = spi, out = x + softmax(QK^T/sqrt(d)+spi) @ V
// BM=32 rows/WG, BN=64 cols/iter, 512 threads = 8 waves.
// S-phase: wave w computes S-tile (mt=w&1 rows 16, nt=w>>2.. cols 16).
// PV-phase: wave w owns d-slice [64w, 64w+64).
// K-tile in LDS via global_load_lds with XOR chunk swizzle (bank-conflict-free frags).
__global__ __launch_bounds__(512, 2) void flash_attn(const bf16* __restrict__ nx,
                                                     const bf16* __restrict__ nxT,
                                                     const float* __restrict__ spi,
                                                     const float* __restrict__ x,
                                                     float* __restrict__ out) {
  __shared__ __align__(16) short q_s[32 * EMB];
  __shared__ __align__(16) short k_s[64 * EMB];
  __shared__ __align__(16) short p_s[32 * 72];  // stride 72 (pad) for PV A-frags
  __shared__ float wmax[8][16];
  __shared__ float wsum[8][16];
  __shared__ float alpha_s[32];
  __shared__ float l_s[32];

  const int tid = threadIdx.x;
  const int wave = tid >> 6;
  const int lane = tid & 63;
  const int quad = lane >> 4;
  const int l16 = lane & 15;
  const int mt = wave & 1;
  const int nt = wave >> 1;  // 0..3
  const int q0 = blockIdx.x * 32;

  floatx4 O[2][4];
#pragma unroll
  for (int a = 0; a < 2; ++a)
#pragma unroll
    for (int d = 0; d < 4; ++d) O[a][d] = (floatx4){0.f, 0.f, 0.f, 0.f};
  float m_reg[4];
#pragma unroll
  for (int r = 0; r < 4; ++r) m_reg[r] = -INFINITY;
  if (tid < 32) l_s[tid] = 0.f;

  // stage Q (swizzled chunks: physical chunk pc in row r holds logical chunk pc^(r&7))
#pragma unroll
  for (int t = 0; t < 4; ++t) {
    int c = tid + t * 512;  // 0..2047
    int row = c >> 6, cc = c & 63;
    *(uint4*)(q_s + c * 8) =
        *(const uint4*)(nx + (size_t)(q0 + row) * EMB + ((cc ^ (row & 7)) << 3));
  }
  // stage K tile 0 (async; dest base wave-uniform, lane supplies +lane*16B)
#pragma unroll
  for (int t = 0; t < 8; ++t) {
    int row = wave * 8 + t;
    async16(nx + (size_t)row * EMB + ((lane ^ (row & 7)) << 3), k_s + row * EMB);
  }
  __syncthreads();

  const int qrow = mt * 16 + l16;
  const short* qb = q_s + qrow * EMB;
  const int qx = qrow & 7;
  const int krow = nt * 16 + l16;
  const short* kb = k_s + krow * EMB;
  const int kx = krow & 7;

  for (int n0 = 0; n0 < NT; n0 += 64) {
    // prefetch spi bias (HBM ~900cyc, hidden behind QK^T loop)
    float bias[4];
    {
      const float* sp = spi + (size_t)(q0 + mt * 16 + quad * 4) * NT + n0 + nt * 16 + l16;
#pragma unroll
      for (int r = 0; r < 4; ++r) bias[r] = sp[(size_t)r * NT];
    }
    // ---- S = Q K^T over k=512, two independent MFMA chains
    floatx4 acc0 = (floatx4){0.f, 0.f, 0.f, 0.f}, acc1 = (floatx4){0.f, 0.f, 0.f, 0.f};
#pragma unroll
    for (int ks = 0; ks < 16; ks += 2) {
      short8 a0 = *(const short8*)(qb + (((ks * 4 + quad) ^ qx) << 3));
      short8 b0 = *(const short8*)(kb + (((ks * 4 + quad) ^ kx) << 3));
      acc0 = MFMA16(a0, b0, acc0);
      short8 a1 = *(const short8*)(qb + ((((ks + 1) * 4 + quad) ^ qx) << 3));
      short8 b1 = *(const short8*)(kb + ((((ks + 1) * 4 + quad) ^ kx) << 3));
      acc1 = MFMA16(a1, b1, acc1);
    }
    float sv[4], pm[4];
#pragma unroll
    for (int r = 0; r < 4; ++r) {
      sv[r] = (acc0[r] + acc1[r]) * SCALE + bias[r];
      pm[r] = sv[r];
    }
#pragma unroll
    for (int m = 1; m < 16; m <<= 1)
#pragma unroll
      for (int r = 0; r < 4; ++r) pm[r] = fmaxf(pm[r], __shfl_xor(pm[r], m, 64));
    if (l16 == 0) {
#pragma unroll
      for (int r = 0; r < 4; ++r) wmax[wave][quad * 4 + r] = pm[r];
    }
    __syncthreads();  // B2: wmax visible; all waves done reading k_s
    // stage next K tile (drained by B3's implicit vmcnt(0))
    if (n0 + 64 < NT) {
#pragma unroll
      for (int t = 0; t < 8; ++t) {
        int row = wave * 8 + t;
        async16(nx + (size_t)(n0 + 64 + row) * EMB + ((lane ^ (row & 7)) << 3),
                k_s + row * EMB);
      }
    }
    // ---- online softmax
    float al[4], pv[4], psum[4];
#pragma unroll
    for (int r = 0; r < 4; ++r) {
      int rr = quad * 4 + r;
      float cm = fmaxf(fmaxf(wmax[mt][rr], wmax[mt + 2][rr]),
                       fmaxf(wmax[mt + 4][rr], wmax[mt + 6][rr]));
      float mn = fmaxf(m_reg[r], cm);
      al[r] = __expf(m_reg[r] - mn);
      m_reg[r] = mn;
      pv[r] = __expf(sv[r] - mn);
      psum[r] = pv[r];
    }
#pragma unroll
    for (int m = 1; m < 16; m <<= 1)
#pragma unroll
      for (int r = 0; r < 4; ++r) psum[r] += __shfl_xor(psum[r], m, 64);
    if (l16 == 0) {
#pragma unroll
      for (int r = 0; r < 4; ++r) wsum[wave][quad * 4 + r] = psum[r];
    }
#pragma unroll
    for (int r = 0; r < 4; ++r)
      ((bf16*)p_s)[(mt * 16 + quad * 4 + r) * 72 + nt * 16 + l16] = __float2bfloat16(pv[r]);
    if (wave < 2 && l16 == 0) {
#pragma unroll
      for (int r = 0; r < 4; ++r) alpha_s[mt * 16 + quad * 4 + r] = al[r];
    }
    __syncthreads();  // B3: p_s/wsum/alpha_s visible; next K staged
    if (wave < 2 && l16 == 0) {
#pragma unroll
      for (int r = 0; r < 4; ++r) {
        int rr = quad * 4 + r;
        l_s[mt * 16 + rr] = al[r] * l_s[mt * 16 + rr] + wsum[mt][rr] + wsum[mt + 2][rr] +
                            wsum[mt + 4][rr] + wsum[mt + 6][rr];
      }
    }
    // ---- rescale O
    float arow[2][4];
#pragma unroll
    for (int a = 0; a < 2; ++a)
#pragma unroll
      for (int r = 0; r < 4; ++r) arow[a][r] = alpha_s[a * 16 + quad * 4 + r];
#pragma unroll
    for (int a = 0; a < 2; ++a)
#pragma unroll
      for (int d = 0; d < 4; ++d)
#pragma unroll
        for (int r = 0; r < 4; ++r) O[a][d][r] *= arow[a][r];
    // ---- PV: O += P @ V  (V-frags straight from nxT, 16B contiguous)
#pragma unroll
    for (int ns = 0; ns < 2; ++ns) {
      short8 pa0 = *(const short8*)(p_s + (l16)*72 + ns * 32 + quad * 8);
      short8 pa1 = *(const short8*)(p_s + (16 + l16) * 72 + ns * 32 + quad * 8);
#pragma unroll
      for (int d = 0; d < 4; ++d) {
        short8 vb = *(const short8*)((const short*)nxT +
                                     (size_t)(wave * 64 + d * 16 + l16) * NT + n0 +
                                     ns * 32 + quad * 8);
        O[0][d] = MFMA16(pa0, vb, O[0][d]);
        O[1][d] = MFMA16(pa1, vb, O[1][d]);
      }
    }
  }
  __syncthreads();
  // ---- epilogue: out = x + O / l
  float linv[2][4];
#pragma unroll
  for (int a = 0; a < 2; ++a)
#pragma unroll
    for (int r = 0; r < 4; ++r) linv[a][r] = 1.0f / l_s[a * 16 + quad * 4 + r];
#pragma unroll
  for (int a = 0; a < 2; ++a)
#pragma unroll
    for (int d = 0; d < 4; ++d)
#pragma unroll
      for (int r = 0; r < 4; ++r) {
        size_t idx = (size_t)(q0 + a * 16 + quad * 4 + r) * EMB + wave * 64 + d * 16 + l16;
        out[idx] = x[idx] + O[a][d][r] * linv[a][r];
      }
}

// ---------------- BT-GEMM: C[i][j] = sum_k A[i][k]*BT[j][k], 128x128 tile ----------------
// MODE 0: C = relu(acc + bias[j]) -> bf16    MODE 1: C = acc + bias[j] + resid -> fp32
template <int MODE>
__global__ __launch_bounds__(256) void gemm_bt(const bf16* __restrict__ A,
                                               const bf16* __restrict__ BT,
                                               const float* __restrict__ bias,
                                               const float* __restrict__ resid,
                                               void* __restrict__ Cout, int M, int Nn,
                                               int K) {
  __shared__ __align__(16) short a_s[128 * 32];
  __shared__ __align__(16) short b_s[128 * 32];
  const int tid = threadIdx.x;
  const int wave = tid >> 6, lane = tid & 63, quad = lane >> 4, l16 = lane & 15;
  const int m0 = blockIdx.x * 128, n0 = blockIdx.y * 128;
  const int mh = (wave & 1) * 64, nh = (wave >> 1) * 64;

  floatx4 acc[4][4];
#pragma unroll
  for (int i = 0; i < 4; ++i)
#pragma unroll
    for (int j = 0; j < 4; ++j) acc[i][j] = (floatx4){0.f, 0.f, 0.f, 0.f};

  for (int k0 = 0; k0 < K; k0 += 32) {
    __syncthreads();
#pragma unroll
    for (int t = 0; t < 2; ++t) {
      int c = (wave * 2 + t) * 64 + lane;  // chunk 0..511
      int row = c >> 2, pc = c & 3;
      int sc = (pc ^ ((row >> 1) & 3)) << 3;  // XOR swizzle source col
      async16(A + (size_t)(m0 + row) * K + k0 + sc, a_s + (wave * 2 + t) * 512);
      async16(BT + (size_t)(n0 + row) * K + k0 + sc, b_s + (wave * 2 + t) * 512);
    }
    __syncthreads();
    short8 af[4], bfr[4];
#pragma unroll
    for (int i = 0; i < 4; ++i) {
      int ar = mh + i * 16 + l16;
      af[i] = *(const short8*)(a_s + ar * 32 + ((quad ^ ((ar >> 1) & 3)) << 3));
      int br = nh + i * 16 + l16;
      bfr[i] = *(const short8*)(b_s + br * 32 + ((quad ^ ((br >> 1) & 3)) << 3));
    }
#pragma unroll
    for (int i = 0; i < 4; ++i)
#pragma unroll
      for (int j = 0; j < 4; ++j) acc[i][j] = MFMA16(af[i], bfr[j], acc[i][j]);
  }
#pragma unroll
  for (int i = 0; i < 4; ++i)
#pragma unroll
    for (int j = 0; j < 4; ++j)
#pragma unroll
      for (int r = 0; r < 4; ++r) {
        int row = m0 + mh + i * 16 + quad * 4 + r;
        int col = n0 + nh + j * 16 + l16;
        float v = acc[i][j][r] + bias[col];
        if (MODE == 0) {
          ((bf16*)Cout)[(size_t)row * Nn + col] = __float2bfloat16(fmaxf(v, 0.f));
        } else {
          size_t idx = (size_t)row * Nn + col;
          ((float*)Cout)[idx] = v + resid[idx];
        }
      }
}

// ---------------- launch ----------------
extern "C" void kernel_launch(void* const* d_in, const int* in_sizes, int n_in,
                              void* d_out, int out_size, void* d_ws, size_t ws_size,
                              hipStream_t stream) {
  const float* x = (const float*)d_in[0];
  // d_in[1] = edge_weights (unused by reference)
  const float* spi = (const float*)d_in[2];
  const float* g1 = (const float*)d_in[3];
  const float* b1 = (const float*)d_in[4];
  const float* g2 = (const float*)d_in[5];
  const float* b2 = (const float*)d_in[6];
  const float* W1 = (const float*)d_in[7];
  const float* bb1 = (const float*)d_in[8];
  const float* W2 = (const float*)d_in[9];
  const float* bb2 = (const float*)d_in[10];
  float* out = (float*)d_out;

  // workspace layout (needs 60 MB)
  char* ws = (char*)d_ws;
  bf16* nx = (bf16*)(ws);                          //  8 MB  [NT][EMB]
  bf16* nxT = (bf16*)(ws + (8ull << 20));          //  8 MB  [EMB][NT]
  bf16* h = (bf16*)(ws + (16ull << 20));           //  8 MB  [NT][EMB]
  bf16* t = (bf16*)(ws + (24ull << 20));           // 32 MB  [NT][DFF]
  bf16* w1t = (bf16*)(ws + (56ull << 20));         //  2 MB  [DFF][EMB]
  bf16* w2t = (bf16*)(ws + (58ull << 20));         //  2 MB  [EMB][DFF]

  ln_kernel<<<NT, 512, 0, stream>>>(x, g1, b1, nx);
  transpose_cast<bf16><<<dim3(NT / 32, EMB / 32), dim3(32, 8), 0, stream>>>(nx, nxT, NT, EMB);
  transpose_cast<float><<<dim3(EMB / 32, DFF / 32), dim3(32, 8), 0, stream>>>(W1, w1t, EMB, DFF);
  transpose_cast<float><<<dim3(DFF / 32, EMB / 32), dim3(32, 8), 0, stream>>>(W2, w2t, DFF, EMB);
  flash_attn<<<NT / 32, 512, 0, stream>>>(nx, nxT, spi, x, out);
  ln_kernel<<<NT, 512, 0, stream>>>(out, g2, b2, h);
  gemm_bt<0><<<dim3(NT / 128, DFF / 128), 256, 0, stream>>>(h, w1t, bb1, nullptr, (void*)t, NT, DFF, EMB);
  gemm_bt<1><<<dim3(NT / 128, EMB / 128), 256, 0, stream>>>(t, w2t, bb2, out, (void*)out, NT, EMB, DFF);
}

// Round 2
// 984.539 us; speedup vs baseline: 1.0048x; 1.0048x over previous
//
#include <hip/hip_runtime.h>
#include <hip/hip_bf16.h>
#include <math.h>

// Problem constants (fixed by reference)
#define NT  8192
#define EMB 512
#define DFF 2048
#define EPS 1e-5f
#define SCALE 0.04419417382415922f  // 1/sqrt(512)

typedef __hip_bfloat16 bf16;
typedef __attribute__((ext_vector_type(8))) short short8;
typedef __attribute__((ext_vector_type(4))) float floatx4;

#define MFMA16(a, b, c) __builtin_amdgcn_mfma_f32_16x16x32_bf16((a), (b), (c), 0, 0, 0)

// raw barriers: do NOT drain vmcnt (B1) / drain everything (B2).
// asm memory clobber pins LDS/global ops on either side.
#define BARRIER_LGKM() asm volatile("s_waitcnt lgkmcnt(0)\ns_barrier" ::: "memory")
#define BARRIER_ALL()  asm volatile("s_waitcnt vmcnt(0) lgkmcnt(0)\ns_barrier" ::: "memory")

__device__ __forceinline__ void async16(const void* g, void* l) {
  __builtin_amdgcn_global_load_lds(
      (const __attribute__((address_space(1))) void*)g,
      (__attribute__((address_space(3))) void*)l, 16, 0, 0);
}

// ---------------- LayerNorm: fp32 in -> bf16 out, one row per block ----------------
__global__ __launch_bounds__(512) void ln_kernel(const float* __restrict__ in,
                                                 const float* __restrict__ g,
                                                 const float* __restrict__ b,
                                                 bf16* __restrict__ out) {
  const int row = blockIdx.x;
  const int tid = threadIdx.x;
  float v = in[(size_t)row * EMB + tid];
  float s = v, ss = v * v;
#pragma unroll
  for (int m = 1; m < 64; m <<= 1) {
    s += __shfl_xor(s, m, 64);
    ss += __shfl_xor(ss, m, 64);
  }
  __shared__ float ps[8], pss[8], mu_s, ri_s;
  const int wave = tid >> 6;
  if ((tid & 63) == 0) { ps[wave] = s; pss[wave] = ss; }
  __syncthreads();
  if (tid == 0) {
    float S = 0.f, SS = 0.f;
#pragma unroll
    for (int w = 0; w < 8; ++w) { S += ps[w]; SS += pss[w]; }
    float mu = S * (1.0f / EMB);
    float var = SS * (1.0f / EMB) - mu * mu;
    mu_s = mu;
    ri_s = rsqrtf(var + EPS);
  }
  __syncthreads();
  float y = (v - mu_s) * ri_s * g[tid] + b[tid];
  out[(size_t)row * EMB + tid] = __float2bfloat16(y);
}

// ---------------- transpose + cast to bf16: out[c][r] = in[r][c] ----------------
template <typename Tin>
__global__ void transpose_cast(const Tin* __restrict__ in, bf16* __restrict__ out,
                               int R, int C) {
  __shared__ float tile[32][33];
  const int r0 = blockIdx.x * 32, c0 = blockIdx.y * 32;
  const int x = threadIdx.x, y = threadIdx.y;  // block (32, 8)
#pragma unroll
  for (int i = 0; i < 4; ++i)
    tile[y + 8 * i][x] = (float)in[(size_t)(r0 + y + 8 * i) * C + c0 + x];
  __syncthreads();
#pragma unroll
  for (int i = 0; i < 4; ++i)
    out[(size_t)(c0 + y + 8 * i) * R + r0 + x] = __float2bfloat16(tile[x][y + 8 * i]);
}

// ---------------- Flash attention (v2: dbuf K, Q in regs, raw barriers) ----------------
// Q=K=V=norm_x (bf16), bias = spi, out = x + softmax(QK^T/sqrt(d)+spi) @ V
// BM=32 rows/WG, BN=64 cols/iter, 512 threads = 8 waves.
// S-phase: wave w -> tile rows (w&1)*16, cols (w>>1)*16.  PV: wave w owns dims [64w,64w+64).
// Per-iter: stage k_s[next] + prefetch spi/V at TOP; B1 = lgkm-only barrier (staging
// stays in flight); B2 = vmcnt(0)+barrier (staging had QK+softmax to land).
__global__ __launch_bounds__(512, 2) void flash_attn(const bf16* __restrict__ nx,
                                                     const bf16* __restrict__ nxT,
                                                     const float* __restrict__ spi,
                                                     const float* __restrict__ x,
                                                     float* __restrict__ out) {
  __shared__ __align__(16) short k_s[2 * 64 * EMB];  // 128 KB double buffer
  __shared__ __align__(16) short p_s[32 * 72];       // stride 72 (pad) for PV A-frags
  __shared__ float wmax[8][16];
  __shared__ float wsum[8][16];
  __shared__ float alpha_s[32];
  __shared__ float l_s[32];

  const int tid = threadIdx.x;
  const int wave = tid >> 6;
  const int lane = tid & 63;
  const int quad = lane >> 4;
  const int l16 = lane & 15;
  const int mt = wave & 1;
  const int nt = wave >> 1;  // 0..3
  const int q0 = blockIdx.x * 32;

  floatx4 O[2][4];
#pragma unroll
  for (int a = 0; a < 2; ++a)
#pragma unroll
    for (int d = 0; d < 4; ++d) O[a][d] = (floatx4){0.f, 0.f, 0.f, 0.f};
  float m_reg[4];
#pragma unroll
  for (int r = 0; r < 4; ++r) m_reg[r] = -INFINITY;
  if (tid < 32) l_s[tid] = 0.f;

  // ---- Q tile into registers: 16 A-frags covering k=0..511 for rows mt*16+l16
  short8 qf[16];
  {
    const short* qp = (const short*)nx + (size_t)(q0 + mt * 16 + l16) * EMB + quad * 8;
#pragma unroll
    for (int ks = 0; ks < 16; ++ks) qf[ks] = *(const short8*)(qp + ks * 32);
  }
  // ---- stage K tile 0 into buffer 0 (async, XOR chunk swizzle)
#pragma unroll
  for (int t = 0; t < 8; ++t) {
    int row = wave * 8 + t;
    async16(nx + (size_t)row * EMB + ((lane ^ (row & 7)) << 3), k_s + row * EMB);
  }
  __syncthreads();  // full sync: Q regs loaded, buf0 staged, l_s init

  const int krow = nt * 16 + l16;
  const int kx = krow & 7;

  for (int n0 = 0; n0 < NT; n0 += 64) {
    const int cb = (n0 >> 6) & 1;
    const short* kb = k_s + cb * (64 * EMB) + krow * EMB;

    // ---- iter-top prefetches (all complete by B2's vmcnt(0)) ----
    // spi bias (consumed right after QK)
    float bias[4];
    {
      const float* sp = spi + (size_t)(q0 + mt * 16 + quad * 4) * NT + n0 + nt * 16 + l16;
#pragma unroll
      for (int r = 0; r < 4; ++r) bias[r] = sp[(size_t)r * NT];
    }
    // stage NEXT K tile into the other buffer (its last readers finished pre-B1 last iter)
    if (n0 + 64 < NT) {
      short* kn = k_s + (cb ^ 1) * (64 * EMB);
#pragma unroll
      for (int t = 0; t < 8; ++t) {
        int row = wave * 8 + t;
        async16(nx + (size_t)(n0 + 64 + row) * EMB + ((lane ^ (row & 7)) << 3),
                kn + row * EMB);
      }
    }
    // V fragments for THIS iter's PV (consumed after B2)
    short8 vf[8];
#pragma unroll
    for (int ns = 0; ns < 2; ++ns)
#pragma unroll
      for (int d = 0; d < 4; ++d)
        vf[ns * 4 + d] = *(const short8*)((const short*)nxT +
                                          (size_t)(wave * 64 + d * 16 + l16) * NT + n0 +
                                          ns * 32 + quad * 8);

    // ---- S = Q K^T over k=512, two independent MFMA chains
    floatx4 acc0 = (floatx4){0.f, 0.f, 0.f, 0.f}, acc1 = (floatx4){0.f, 0.f, 0.f, 0.f};
#pragma unroll
    for (int ks = 0; ks < 16; ks += 2) {
      short8 b0 = *(const short8*)(kb + (((ks * 4 + quad) ^ kx) << 3));
      acc0 = MFMA16(qf[ks], b0, acc0);
      short8 b1 = *(const short8*)(kb + ((((ks + 1) * 4 + quad) ^ kx) << 3));
      acc1 = MFMA16(qf[ks + 1], b1, acc1);
    }
    float sv[4], pm[4];
#pragma unroll
    for (int r = 0; r < 4; ++r) {
      sv[r] = (acc0[r] + acc1[r]) * SCALE + bias[r];
      pm[r] = sv[r];
    }
#pragma unroll
    for (int m = 1; m < 16; m <<= 1)
#pragma unroll
      for (int r = 0; r < 4; ++r) pm[r] = fmaxf(pm[r], __shfl_xor(pm[r], m, 64));
    if (l16 == 0) {
#pragma unroll
      for (int r = 0; r < 4; ++r) wmax[wave][quad * 4 + r] = pm[r];
    }
    BARRIER_LGKM();  // B1: wmax visible; staging stays in flight (no vmcnt drain)

    // ---- online softmax
    float al[4], pv[4], psum[4];
#pragma unroll
    for (int r = 0; r < 4; ++r) {
      int rr = quad * 4 + r;
      float cm = fmaxf(fmaxf(wmax[mt][rr], wmax[mt + 2][rr]),
                       fmaxf(wmax[mt + 4][rr], wmax[mt + 6][rr]));
      float mn = fmaxf(m_reg[r], cm);
      al[r] = __expf(m_reg[r] - mn);
      m_reg[r] = mn;
      pv[r] = __expf(sv[r] - mn);
      psum[r] = pv[r];
    }
#pragma unroll
    for (int m = 1; m < 16; m <<= 1)
#pragma unroll
      for (int r = 0; r < 4; ++r) psum[r] += __shfl_xor(psum[r], m, 64);
    if (l16 == 0) {
#pragma unroll
      for (int r = 0; r < 4; ++r) wsum[wave][quad * 4 + r] = psum[r];
    }
#pragma unroll
    for (int r = 0; r < 4; ++r)
      ((bf16*)p_s)[(mt * 16 + quad * 4 + r) * 72 + nt * 16 + l16] = __float2bfloat16(pv[r]);
    if (wave < 2 && l16 == 0) {
#pragma unroll
      for (int r = 0; r < 4; ++r) alpha_s[mt * 16 + quad * 4 + r] = al[r];
    }
    BARRIER_ALL();  // B2: p_s/wsum/alpha_s visible; next-K staging + V prefetch drained

    if (wave < 2 && l16 == 0) {
#pragma unroll
      for (int r = 0; r < 4; ++r) {
        int rr = quad * 4 + r;
        l_s[mt * 16 + rr] = al[r] * l_s[mt * 16 + rr] + wsum[mt][rr] + wsum[mt + 2][rr] +
                            wsum[mt + 4][rr] + wsum[mt + 6][rr];
      }
    }
    // ---- rescale O
    float arow[2][4];
#pragma unroll
    for (int a = 0; a < 2; ++a)
#pragma unroll
      for (int r = 0; r < 4; ++r) arow[a][r] = alpha_s[a * 16 + quad * 4 + r];
#pragma unroll
    for (int a = 0; a < 2; ++a)
#pragma unroll
      for (int d = 0; d < 4; ++d)
#pragma unroll
        for (int r = 0; r < 4; ++r) O[a][d][r] *= arow[a][r];
    // ---- PV: O += P @ V  (V-frags already in registers)
#pragma unroll
    for (int ns = 0; ns < 2; ++ns) {
      short8 pa0 = *(const short8*)(p_s + (l16)*72 + ns * 32 + quad * 8);
      short8 pa1 = *(const short8*)(p_s + (16 + l16) * 72 + ns * 32 + quad * 8);
#pragma unroll
      for (int d = 0; d < 4; ++d) {
        O[0][d] = MFMA16(pa0, vf[ns * 4 + d], O[0][d]);
        O[1][d] = MFMA16(pa1, vf[ns * 4 + d], O[1][d]);
      }
    }
  }
  __syncthreads();
  // ---- epilogue: out = x + O / l
  float linv[2][4];
#pragma unroll
  for (int a = 0; a < 2; ++a)
#pragma unroll
    for (int r = 0; r < 4; ++r) linv[a][r] = 1.0f / l_s[a * 16 + quad * 4 + r];
#pragma unroll
  for (int a = 0; a < 2; ++a)
#pragma unroll
    for (int d = 0; d < 4; ++d)
#pragma unroll
      for (int r = 0; r < 4; ++r) {
        size_t idx = (size_t)(q0 + a * 16 + quad * 4 + r) * EMB + wave * 64 + d * 16 + l16;
        out[idx] = x[idx] + O[a][d][r] * linv[a][r];
      }
}

// ---------------- BT-GEMM: C[i][j] = sum_k A[i][k]*BT[j][k], 128x128 tile ----------------
// MODE 0: C = relu(acc + bias[j]) -> bf16    MODE 1: C = acc + bias[j] + resid -> fp32
template <int MODE>
__global__ __launch_bounds__(256) void gemm_bt(const bf16* __restrict__ A,
                                               const bf16* __restrict__ BT,
                                               const float* __restrict__ bias,
                                               const float* __restrict__ resid,
                                               void* __restrict__ Cout, int M, int Nn,
                                               int K) {
  __shared__ __align__(16) short a_s[128 * 32];
  __shared__ __align__(16) short b_s[128 * 32];
  const int tid = threadIdx.x;
  const int wave = tid >> 6, lane = tid & 63, quad = lane >> 4, l16 = lane & 15;
  const int m0 = blockIdx.x * 128, n0 = blockIdx.y * 128;
  const int mh = (wave & 1) * 64, nh = (wave >> 1) * 64;

  floatx4 acc[4][4];
#pragma unroll
  for (int i = 0; i < 4; ++i)
#pragma unroll
    for (int j = 0; j < 4; ++j) acc[i][j] = (floatx4){0.f, 0.f, 0.f, 0.f};

  for (int k0 = 0; k0 < K; k0 += 32) {
    __syncthreads();
#pragma unroll
    for (int t = 0; t < 2; ++t) {
      int c = (wave * 2 + t) * 64 + lane;  // chunk 0..511
      int row = c >> 2, pc = c & 3;
      int sc = (pc ^ ((row >> 1) & 3)) << 3;  // XOR swizzle source col
      async16(A + (size_t)(m0 + row) * K + k0 + sc, a_s + (wave * 2 + t) * 512);
      async16(BT + (size_t)(n0 + row) * K + k0 + sc, b_s + (wave * 2 + t) * 512);
    }
    __syncthreads();
    short8 af[4], bfr[4];
#pragma unroll
    for (int i = 0; i < 4; ++i) {
      int ar = mh + i * 16 + l16;
      af[i] = *(const short8*)(a_s + ar * 32 + ((quad ^ ((ar >> 1) & 3)) << 3));
      int br = nh + i * 16 + l16;
      bfr[i] = *(const short8*)(b_s + br * 32 + ((quad ^ ((br >> 1) & 3)) << 3));
    }
#pragma unroll
    for (int i = 0; i < 4; ++i)
#pragma unroll
      for (int j = 0; j < 4; ++j) acc[i][j] = MFMA16(af[i], bfr[j], acc[i][j]);
  }
#pragma unroll
  for (int i = 0; i < 4; ++i)
#pragma unroll
    for (int j = 0; j < 4; ++j)
#pragma unroll
      for (int r = 0; r < 4; ++r) {
        int row = m0 + mh + i * 16 + quad * 4 + r;
        int col = n0 + nh + j * 16 + l16;
        float v = acc[i][j][r] + bias[col];
        if (MODE == 0) {
          ((bf16*)Cout)[(size_t)row * Nn + col] = __float2bfloat16(fmaxf(v, 0.f));
        } else {
          size_t idx = (size_t)row * Nn + col;
          ((float*)Cout)[idx] = v + resid[idx];
        }
      }
}

// ---------------- launch ----------------
extern "C" void kernel_launch(void* const* d_in, const int* in_sizes, int n_in,
                              void* d_out, int out_size, void* d_ws, size_t ws_size,
                              hipStream_t stream) {
  const float* x = (const float*)d_in[0];
  // d_in[1] = edge_weights (unused by reference)
  const float* spi = (const float*)d_in[2];
  const float* g1 = (const float*)d_in[3];
  const float* b1 = (const float*)d_in[4];
  const float* g2 = (const float*)d_in[5];
  const float* b2 = (const float*)d_in[6];
  const float* W1 = (const float*)d_in[7];
  const float* bb1 = (const float*)d_in[8];
  const float* W2 = (const float*)d_in[9];
  const float* bb2 = (const float*)d_in[10];
  float* out = (float*)d_out;

  // workspace layout (needs 60 MB)
  char* ws = (char*)d_ws;
  bf16* nx = (bf16*)(ws);                          //  8 MB  [NT][EMB]
  bf16* nxT = (bf16*)(ws + (8ull << 20));          //  8 MB  [EMB][NT]
  bf16* h = (bf16*)(ws + (16ull << 20));           //  8 MB  [NT][EMB]
  bf16* t = (bf16*)(ws + (24ull << 20));           // 32 MB  [NT][DFF]
  bf16* w1t = (bf16*)(ws + (56ull << 20));         //  2 MB  [DFF][EMB]
  bf16* w2t = (bf16*)(ws + (58ull << 20));         //  2 MB  [EMB][DFF]

  ln_kernel<<<NT, 512, 0, stream>>>(x, g1, b1, nx);
  transpose_cast<bf16><<<dim3(NT / 32, EMB / 32), dim3(32, 8), 0, stream>>>(nx, nxT, NT, EMB);
  transpose_cast<float><<<dim3(EMB / 32, DFF / 32), dim3(32, 8), 0, stream>>>(W1, w1t, EMB, DFF);
  transpose_cast<float><<<dim3(DFF / 32, EMB / 32), dim3(32, 8), 0, stream>>>(W2, w2t, DFF, EMB);
  flash_attn<<<NT / 32, 512, 0, stream>>>(nx, nxT, spi, x, out);
  ln_kernel<<<NT, 512, 0, stream>>>(out, g2, b2, h);
  gemm_bt<0><<<dim3(NT / 128, DFF / 128), 256, 0, stream>>>(h, w1t, bb1, nullptr, (void*)t, NT, DFF, EMB);
  gemm_bt<1><<<dim3(NT / 128, EMB / 128), 256, 0, stream>>>(t, w2t, bb2, out, (void*)out, NT, EMB, DFF);
}